// Round 3
// baseline (27793.384 us; speedup 1.0000x reference)
//
#include <hip/hip_runtime.h>

#define T_LEN 512
#define BATCH 32
#define HSZ 512
#define G3 1536
#define NBLK_REC 32

typedef unsigned int u32;
typedef unsigned long long u64;
typedef unsigned short u16;
typedef __attribute__((ext_vector_type(8))) short bf16x8;
typedef __attribute__((ext_vector_type(4))) float f32x4;

// ---------- helpers ----------
static __device__ __forceinline__ u16 f2bf(float x) {
  u32 u = __float_as_uint(x);
  u32 r = (u + 0x7FFFu + ((u >> 16) & 1u)) >> 16;
  return (u16)r;
}
static __device__ __forceinline__ float nz(float x) { return (x == x) ? x : 0.f; }

// device-scope grid barrier: monotonic arrival counter + epoch flag
static __device__ __forceinline__ void gridbar(int* cnt, int* epoch, int step) {
  __syncthreads();
  if (threadIdx.x == 0) {
    int prev = __hip_atomic_fetch_add(cnt, 1, __ATOMIC_ACQ_REL, __HIP_MEMORY_SCOPE_AGENT);
    int target = NBLK_REC * (step + 1);
    if (prev == target - 1) {
      __hip_atomic_store(epoch, step + 1, __ATOMIC_RELEASE, __HIP_MEMORY_SCOPE_AGENT);
    } else {
      while (__hip_atomic_load(epoch, __ATOMIC_ACQUIRE, __HIP_MEMORY_SCOPE_AGENT) < step + 1)
        __builtin_amdgcn_s_sleep(2);
    }
  }
  __syncthreads();
}

// ---------- conversion kernels ----------
// [2][K][N] f32 -> [2][N][K] bf16 (transpose per dir)
__global__ __launch_bounds__(256) void transpose_bf16(
    const float* __restrict__ src, u16* __restrict__ dst, int K, int N)
{
  int dirz = blockIdx.z;
  src += (size_t)dirz * K * N;
  dst += (size_t)dirz * N * K;
  __shared__ float tile[32][33];
  int n0 = blockIdx.x * 32, k0 = blockIdx.y * 32;
  int tx = threadIdx.x & 31, ty = threadIdx.x >> 5;
#pragma unroll
  for (int i = ty; i < 32; i += 8)
    tile[i][tx] = src[(size_t)(k0 + i) * N + n0 + tx];
  __syncthreads();
#pragma unroll
  for (int i = ty; i < 32; i += 8)
    dst[(size_t)(n0 + i) * K + k0 + tx] = f2bf(tile[tx][i]);
}

__global__ __launch_bounds__(256) void convert_x(
    const float* __restrict__ src, u16* __restrict__ dst, int n4)
{
  int i = blockIdx.x * 256 + threadIdx.x;
  if (i >= n4) return;
  float4 v = ((const float4*)src)[i];
  union { u16 h[4]; uint2 u; } o;
  o.h[0] = f2bf(v.x); o.h[1] = f2bf(v.y); o.h[2] = f2bf(v.z); o.h[3] = f2bf(v.w);
  ((uint2*)dst)[i] = o.u;
}

// ---------- input-gate GEMM ----------
// C[dir][M][N] = A[M][K] @ B[dir][N][K]^T + bias[dir][N]  (bf16 in, fp16 out)
// 128x128 tile, 256 threads (4 waves 2x2), each wave 64x64 = 4x4 frags of 16x16x32
__global__ __launch_bounds__(256) void gemm_gi(
    const u16* __restrict__ A,   // [M][K] bf16
    const u16* __restrict__ Bw,  // [2][N][K] bf16
    const float* __restrict__ bias,
    _Float16* __restrict__ C,    // [2][M][N]
    int M, int K)
{
  const int N = G3;
  int dir = blockIdx.z;
  const u16* Bd = Bw + (size_t)dir * N * K;
  _Float16* Cd = C + (size_t)dir * M * N;
  const float* biasd = bias + dir * N;

  int tm = blockIdx.x * 128;
  int tn = blockIdx.y * 128;

  __shared__ u16 sA[128][40];
  __shared__ u16 sB[128][40];

  int tid = threadIdx.x;
  int lane = tid & 63, wave = tid >> 6;
  int wm = (wave & 1) << 6, wn = (wave >> 1) << 6;

  f32x4 acc[4][4] = {};

  // staging: 2 threads per 128-row, each covers 16 elements (32 B) via two uint4
  int srow = tid >> 1, shalf = (tid & 1) << 4;
  const u16* pa = A + (size_t)(tm + srow) * K + shalf;
  const u16* pb = Bd + (size_t)(tn + srow) * K + shalf;

  for (int k0 = 0; k0 < K; k0 += 32) {
    uint4 va0 = *(const uint4*)(pa + k0);
    uint4 va1 = *(const uint4*)(pa + k0 + 8);
    uint4 vb0 = *(const uint4*)(pb + k0);
    uint4 vb1 = *(const uint4*)(pb + k0 + 8);
    *(uint4*)&sA[srow][shalf]     = va0;
    *(uint4*)&sA[srow][shalf + 8] = va1;
    *(uint4*)&sB[srow][shalf]     = vb0;
    *(uint4*)&sB[srow][shalf + 8] = vb1;
    __syncthreads();
    int kg = (lane >> 4) << 3;
    int r16 = lane & 15;
    bf16x8 af[4], bfr[4];
#pragma unroll
    for (int f = 0; f < 4; f++) {
      af[f]  = *(const bf16x8*)&sA[wm + f * 16 + r16][kg];
      bfr[f] = *(const bf16x8*)&sB[wn + f * 16 + r16][kg];
    }
#pragma unroll
    for (int fm = 0; fm < 4; fm++)
#pragma unroll
      for (int fn = 0; fn < 4; fn++)
        acc[fm][fn] = __builtin_amdgcn_mfma_f32_16x16x32_bf16(af[fm], bfr[fn], acc[fm][fn], 0, 0, 0);
    __syncthreads();
  }

  int col4 = lane & 15, rbase = (lane >> 4) << 2;
#pragma unroll
  for (int fn = 0; fn < 4; fn++) {
    int col = tn + wn + fn * 16 + col4;
    float bv = biasd[col];
#pragma unroll
    for (int fm = 0; fm < 4; fm++) {
      int row0 = tm + wm + fm * 16 + rbase;
#pragma unroll
      for (int r = 0; r < 4; r++)
        Cd[(size_t)(row0 + r) * N + col] = (_Float16)nz(acc[fm][fn][r] + bv);
    }
  }
}

// ---------- persistent recurrent kernel ----------
// 32 blocks: (dir 2) x (m-half 2) x (j-group 8). h transported as fp32.
__global__ __launch_bounds__(256) void gru_rec(
    const _Float16* __restrict__ gi,   // [2][T][B][G3] fp16
    const u16* __restrict__ whhT,      // [2][G3][HSZ] bf16
    const float* __restrict__ bhh,     // [2][G3]
    const float* __restrict__ h0,      // [2][B][HSZ]
    float* __restrict__ outF,          // [T][B][1024] or null
    u16* __restrict__ outB,            // [T][B][1024] bf16 or null
    float* __restrict__ hbuf,          // [2 buf][2 dir][B][HSZ] fp32
    int* __restrict__ cnt, int* __restrict__ epoch)
{
  int bid = blockIdx.x;
  int dir = bid >> 4;
  int mt = (bid >> 3) & 1;
  int jg = bid & 7;
  int lane = threadIdx.x & 63, wave = threadIdx.x >> 6;
  int j = jg * 64 + wave * 16 + (lane & 15);
  int rbase = (lane >> 4) << 2;
  int bA = (mt << 4) | (lane & 15);
  int kq = (lane >> 4) << 3;

  const u16* wr = whhT + ((size_t)dir * G3 + j) * HSZ;
  const u16* wz = wr + (size_t)512 * HSZ;
  const u16* wn = wr + (size_t)1024 * HSZ;

  float bhr = bhh[dir * G3 + j];
  float bhz = bhh[dir * G3 + 512 + j];
  float bhn = bhh[dir * G3 + 1024 + j];

  float hm[4];
#pragma unroll
  for (int r = 0; r < 4; r++)
    hm[r] = nz(h0[((size_t)dir * BATCH + (mt * 16 + rbase + r)) * HSZ + j]);

  // publish initial h (fp32) into buffer 0
  {
    float* hb = hbuf + (size_t)dir * (BATCH * HSZ);
#pragma unroll
    for (int r = 0; r < 4; r++) {
      int b = mt * 16 + rbase + r;
      __hip_atomic_store((u32*)&hb[(size_t)b * HSZ + j], __float_as_uint(hm[r]),
                         __ATOMIC_RELAXED, __HIP_MEMORY_SCOPE_AGENT);
    }
  }
  gridbar(cnt, epoch, 0);

  for (int t = 0; t < T_LEN; t++) {
    int cur = t & 1, nxt = cur ^ 1;
    int t_eff = dir ? (T_LEN - 1 - t) : t;
    const float* hsrc = hbuf + ((size_t)cur * 2 + dir) * (BATCH * HSZ);
    float* hdst = hbuf + ((size_t)nxt * 2 + dir) * (BATCH * HSZ);

    const _Float16* gib = gi + (((size_t)dir * T_LEN + t_eff) * BATCH) * G3;
    float gr[4], gz[4], gn[4];
#pragma unroll
    for (int r = 0; r < 4; r++) {
      const _Float16* g = gib + (size_t)(mt * 16 + rbase + r) * G3;
      gr[r] = nz((float)g[j]); gz[r] = nz((float)g[512 + j]); gn[r] = nz((float)g[1024 + j]);
    }

    f32x4 accR = {0.f, 0.f, 0.f, 0.f}, accZ = {0.f, 0.f, 0.f, 0.f}, accN = {0.f, 0.f, 0.f, 0.f};
#pragma unroll 4
    for (int kg = 0; kg < 16; kg++) {
      const float* hp = hsrc + (size_t)bA * HSZ + kg * 32 + kq;
      union { u16 s[8]; bf16x8 v; } ua;
#pragma unroll
      for (int m = 0; m < 4; m++) {
        u64 q = __hip_atomic_load((const u64*)(hp + 2 * m), __ATOMIC_RELAXED, __HIP_MEMORY_SCOPE_AGENT);
        ua.s[2 * m]     = f2bf(__uint_as_float((u32)q));
        ua.s[2 * m + 1] = f2bf(__uint_as_float((u32)(q >> 32)));
      }
      bf16x8 br = *(const bf16x8*)(wr + kg * 32 + kq);
      bf16x8 bz = *(const bf16x8*)(wz + kg * 32 + kq);
      bf16x8 bn = *(const bf16x8*)(wn + kg * 32 + kq);
      accR = __builtin_amdgcn_mfma_f32_16x16x32_bf16(ua.v, br, accR, 0, 0, 0);
      accZ = __builtin_amdgcn_mfma_f32_16x16x32_bf16(ua.v, bz, accZ, 0, 0, 0);
      accN = __builtin_amdgcn_mfma_f32_16x16x32_bf16(ua.v, bn, accN, 0, 0, 0);
    }

#pragma unroll
    for (int r = 0; r < 4; r++) {
      int b = mt * 16 + rbase + r;
      float aR = nz(accR[r]), aZ = nz(accZ[r]), aN = nz(accN[r]);
      float xr = gr[r] + aR + bhr;
      float xz = gz[r] + aZ + bhz;
      xr = fminf(fmaxf(xr, -40.f), 40.f);
      xz = fminf(fmaxf(xz, -40.f), 40.f);
      float rr = 1.f / (1.f + __expf(-xr));
      float zz = 1.f / (1.f + __expf(-xz));
      float xn = gn[r] + rr * (aN + bhn);
      xn = fminf(fmaxf(xn, -15.f), 15.f);
      float e2 = __expf(2.f * xn);
      float nn = (e2 - 1.f) / (e2 + 1.f);
      float hv = (1.f - zz) * nn + zz * hm[r];
      if (!(hv == hv)) hv = 777.f;   // sentinel: NaN reached the gate output
      hm[r] = hv;

      size_t oidx = ((size_t)t_eff * BATCH + b) * 1024 + dir * HSZ + j;
      if (outF) outF[oidx] = hv;
      if (outB) outB[oidx] = f2bf(hv);

      __hip_atomic_store((u32*)&hdst[(size_t)b * HSZ + j], __float_as_uint(hv),
                         __ATOMIC_RELAXED, __HIP_MEMORY_SCOPE_AGENT);
    }
    if (t + 1 < T_LEN) gridbar(cnt, epoch, t + 1);
  }
}

// ---------- launch ----------
extern "C" void kernel_launch(void* const* d_in, const int* in_sizes, int n_in,
                              void* d_out, int out_size, void* d_ws, size_t ws_size,
                              hipStream_t stream)
{
  const float* x  = (const float*)d_in[0];
  const float* h0 = (const float*)d_in[1];
  const float* w_ih[3] = {(const float*)d_in[2], (const float*)d_in[6], (const float*)d_in[10]};
  const float* w_hh[3] = {(const float*)d_in[3], (const float*)d_in[7], (const float*)d_in[11]};
  const float* b_ih[3] = {(const float*)d_in[4], (const float*)d_in[8], (const float*)d_in[12]};
  const float* b_hh[3] = {(const float*)d_in[5], (const float*)d_in[9], (const float*)d_in[13]};

  char* ws = (char*)d_ws;
  size_t off = 0;
  auto alloc = [&](size_t bytes) {
    void* p = ws + off;
    off = (off + bytes + 255) & ~(size_t)255;
    return p;
  };
  int* bar = (int*)alloc(4096);                                  // 3x (cnt, epoch)
  float* hbuf = (float*)alloc((size_t)2 * 2 * BATCH * HSZ * 4);  // fp32 ping-pong
  u16* xbf  = (u16*)alloc((size_t)16384 * 256 * 2);
  u16* lobf = (u16*)alloc((size_t)16384 * 1024 * 2);
  u16* wihT[3];
  wihT[0] = (u16*)alloc((size_t)2 * G3 * 256 * 2);
  wihT[1] = (u16*)alloc((size_t)2 * G3 * 1024 * 2);
  wihT[2] = (u16*)alloc((size_t)2 * G3 * 1024 * 2);
  u16* whhT[3];
  for (int l = 0; l < 3; l++) whhT[l] = (u16*)alloc((size_t)2 * G3 * 512 * 2);
  _Float16* gi = (_Float16*)alloc((size_t)2 * T_LEN * BATCH * G3 * 2);

  hipMemsetAsync(bar, 0, 4096, stream);

  convert_x<<<4096, 256, 0, stream>>>(x, xbf, 16384 * 256 / 4);
  transpose_bf16<<<dim3(48, 8, 2),  256, 0, stream>>>(w_ih[0], wihT[0], 256,  G3);
  transpose_bf16<<<dim3(48, 32, 2), 256, 0, stream>>>(w_ih[1], wihT[1], 1024, G3);
  transpose_bf16<<<dim3(48, 32, 2), 256, 0, stream>>>(w_ih[2], wihT[2], 1024, G3);
  for (int l = 0; l < 3; l++)
    transpose_bf16<<<dim3(48, 16, 2), 256, 0, stream>>>(w_hh[l], whhT[l], 512, G3);

  const int M = T_LEN * BATCH;
  for (int l = 0; l < 3; l++) {
    int K = (l == 0) ? 256 : 1024;
    const u16* Ain = (l == 0) ? xbf : lobf;
    gemm_gi<<<dim3(M / 128, G3 / 128, 2), 256, 0, stream>>>(Ain, wihT[l], b_ih[l], gi, M, K);
    float* oF = (l == 2) ? (float*)d_out : nullptr;
    u16* oB = (l < 2) ? lobf : nullptr;
    gru_rec<<<NBLK_REC, 256, 0, stream>>>(gi, whhT[l], b_hh[l],
                                          h0 + (size_t)l * 2 * BATCH * HSZ,
                                          oF, oB, hbuf,
                                          bar + l * 128, bar + l * 128 + 64);
  }
}

// Round 4
// 10572.273 us; speedup vs baseline: 2.6289x; 2.6289x over previous
//
#include <hip/hip_runtime.h>

#define T_LEN 512
#define BATCH 32
#define HSZ 512
#define G3 1536

typedef unsigned int u32;
typedef unsigned short u16;
typedef __attribute__((ext_vector_type(8))) short bf16x8;
typedef __attribute__((ext_vector_type(4))) float f32x4;

// ---------- helpers ----------
static __device__ __forceinline__ u16 f2bf(float x) {
  u32 u = __float_as_uint(x);
  u32 r = (u + 0x7FFFu + ((u >> 16) & 1u)) >> 16;
  return (u16)r;
}
static __device__ __forceinline__ float nz(float x) { return (x == x) ? x : 0.f; }

// ---------- conversion kernels ----------
__global__ __launch_bounds__(256) void transpose_bf16(
    const float* __restrict__ src, u16* __restrict__ dst, int K, int N)
{
  int dirz = blockIdx.z;
  src += (size_t)dirz * K * N;
  dst += (size_t)dirz * N * K;
  __shared__ float tile[32][33];
  int n0 = blockIdx.x * 32, k0 = blockIdx.y * 32;
  int tx = threadIdx.x & 31, ty = threadIdx.x >> 5;
#pragma unroll
  for (int i = ty; i < 32; i += 8)
    tile[i][tx] = src[(size_t)(k0 + i) * N + n0 + tx];
  __syncthreads();
#pragma unroll
  for (int i = ty; i < 32; i += 8)
    dst[(size_t)(n0 + i) * K + k0 + tx] = f2bf(tile[tx][i]);
}

__global__ __launch_bounds__(256) void convert_x(
    const float* __restrict__ src, u16* __restrict__ dst, int n4)
{
  int i = blockIdx.x * 256 + threadIdx.x;
  if (i >= n4) return;
  float4 v = ((const float4*)src)[i];
  union { u16 h[4]; uint2 u; } o;
  o.h[0] = f2bf(v.x); o.h[1] = f2bf(v.y); o.h[2] = f2bf(v.z); o.h[3] = f2bf(v.w);
  ((uint2*)dst)[i] = o.u;
}

// ---------- input-gate GEMM (unchanged from R3, verified) ----------
__global__ __launch_bounds__(256) void gemm_gi(
    const u16* __restrict__ A,   // [M][K] bf16
    const u16* __restrict__ Bw,  // [2][N][K] bf16
    const float* __restrict__ bias,
    _Float16* __restrict__ C,    // [2][M][N]
    int M, int K)
{
  const int N = G3;
  int dir = blockIdx.z;
  const u16* Bd = Bw + (size_t)dir * N * K;
  _Float16* Cd = C + (size_t)dir * M * N;
  const float* biasd = bias + dir * N;

  int tm = blockIdx.x * 128;
  int tn = blockIdx.y * 128;

  __shared__ u16 sA[128][40];
  __shared__ u16 sB[128][40];

  int tid = threadIdx.x;
  int lane = tid & 63, wave = tid >> 6;
  int wm = (wave & 1) << 6, wn = (wave >> 1) << 6;

  f32x4 acc[4][4] = {};

  int srow = tid >> 1, shalf = (tid & 1) << 4;
  const u16* pa = A + (size_t)(tm + srow) * K + shalf;
  const u16* pb = Bd + (size_t)(tn + srow) * K + shalf;

  for (int k0 = 0; k0 < K; k0 += 32) {
    uint4 va0 = *(const uint4*)(pa + k0);
    uint4 va1 = *(const uint4*)(pa + k0 + 8);
    uint4 vb0 = *(const uint4*)(pb + k0);
    uint4 vb1 = *(const uint4*)(pb + k0 + 8);
    *(uint4*)&sA[srow][shalf]     = va0;
    *(uint4*)&sA[srow][shalf + 8] = va1;
    *(uint4*)&sB[srow][shalf]     = vb0;
    *(uint4*)&sB[srow][shalf + 8] = vb1;
    __syncthreads();
    int kg = (lane >> 4) << 3;
    int r16 = lane & 15;
    bf16x8 af[4], bfr[4];
#pragma unroll
    for (int f = 0; f < 4; f++) {
      af[f]  = *(const bf16x8*)&sA[wm + f * 16 + r16][kg];
      bfr[f] = *(const bf16x8*)&sB[wn + f * 16 + r16][kg];
    }
#pragma unroll
    for (int fm = 0; fm < 4; fm++)
#pragma unroll
      for (int fn = 0; fn < 4; fn++)
        acc[fm][fn] = __builtin_amdgcn_mfma_f32_16x16x32_bf16(af[fm], bfr[fn], acc[fm][fn], 0, 0, 0);
    __syncthreads();
  }

  int col4 = lane & 15, rbase = (lane >> 4) << 2;
#pragma unroll
  for (int fn = 0; fn < 4; fn++) {
    int col = tn + wn + fn * 16 + col4;
    float bv = biasd[col];
#pragma unroll
    for (int fm = 0; fm < 4; fm++) {
      int row0 = tm + wm + fm * 16 + rbase;
#pragma unroll
      for (int r = 0; r < 4; r++)
        Cd[(size_t)(row0 + r) * N + col] = (_Float16)nz(acc[fm][fn][r] + bv);
    }
  }
}

// ---------- persistent recurrent kernel (redesigned) ----------
// 64 blocks x 64 threads (1 wave). block = (dir, jc): 16 j-cols, all 32 batches,
// 3 gates. Weights LDS-resident (48 KB, preloaded once). h transported as plain
// bf16 wide loads/stores bracketed by one agent acquire/release fence per step.
// Barrier: per-block monotonic epoch flags, relaxed polling, 32 participants/dir.
__global__ __launch_bounds__(64, 1) void gru_rec(
    const _Float16* __restrict__ gi,   // [2][T][B][G3] fp16
    const u16* __restrict__ whhT,      // [2][G3][HSZ] bf16
    const float* __restrict__ bhh,     // [2][G3]
    const float* __restrict__ h0,      // [2][B][HSZ]
    float* __restrict__ outF,          // [T][B][1024] or null
    u16* __restrict__ outB,            // [T][B][1024] bf16 or null
    u16* __restrict__ hbuf,            // [2 buf][2 dir][B][HSZ] bf16
    int* __restrict__ flags,           // [2][64] ints (only [dir][0..31] used)
    int base)                          // layer * 513
{
  int dir = blockIdx.x >> 5;
  int jc  = blockIdx.x & 31;
  int lane = threadIdx.x;          // one wave
  int l15 = lane & 15;
  int q   = lane >> 4;             // 0..3
  int j   = jc * 16 + l15;         // this lane's output column (B/C frag n)
  int kq  = q * 8;                 // k offset within 32-k step (A/B frag)

  __shared__ u16 sW[3][16][520];   // [gate][j_loc][k], pad 8 -> 2-way banks max

  // preload weights: 48 rows x 512 k, 16B chunks
  for (int idx = lane; idx < 48 * 64; idx += 64) {
    int row = idx >> 6, c = idx & 63;
    int g = row >> 4, jl = row & 15;
    const u16* src = whhT + ((size_t)dir * G3 + g * 512 + jc * 16 + jl) * HSZ + c * 8;
    *(uint4*)&sW[g][jl][c * 8] = *(const uint4*)src;
  }
  __syncthreads();

  float bhr = bhh[dir * G3 + j];
  float bhz = bhh[dir * G3 + 512 + j];
  float bhn = bhh[dir * G3 + 1024 + j];

  // master h state: rows b = mt*16 + q*4 + r, col j
  float hm[8];
#pragma unroll
  for (int mt = 0; mt < 2; mt++)
#pragma unroll
    for (int r = 0; r < 4; r++)
      hm[mt * 4 + r] = h0[((size_t)dir * BATCH + mt * 16 + q * 4 + r) * HSZ + j];

  // publish h0 (bf16) into buffer 0
  {
    u16* hb = hbuf + ((size_t)0 * 2 + dir) * BATCH * HSZ;
#pragma unroll
    for (int i = 0; i < 8; i++) {
      int b = (i >> 2) * 16 + q * 4 + (i & 3);
      hb[(size_t)b * HSZ + j] = f2bf(hm[i]);
    }
  }
  __builtin_amdgcn_fence(__ATOMIC_RELEASE, "agent");
  if (lane == 0)
    __hip_atomic_store(&flags[dir * 64 + jc], base + 1, __ATOMIC_RELAXED, __HIP_MEMORY_SCOPE_AGENT);

  for (int t = 0; t < T_LEN; t++) {
    int t_eff = dir ? (T_LEN - 1 - t) : t;

    // gi prefetch: independent of barrier, HBM latency hides behind the poll
    const _Float16* gib = gi + (((size_t)dir * T_LEN + t_eff) * BATCH) * G3;
    float gv[3][8];
#pragma unroll
    for (int g = 0; g < 3; g++)
#pragma unroll
      for (int i = 0; i < 8; i++) {
        int b = (i >> 2) * 16 + q * 4 + (i & 3);
        gv[g][i] = (float)gib[(size_t)b * G3 + g * 512 + j];
      }

    // barrier: wait for all 32 producer blocks of this dir to publish h(t)
    {
      int target = base + t + 1;
      const int* fl = &flags[dir * 64 + (lane & 31)];
      while (true) {
        int f = __hip_atomic_load(fl, __ATOMIC_RELAXED, __HIP_MEMORY_SCOPE_AGENT);
        if (__ballot(f >= target) == ~0ull) break;
        __builtin_amdgcn_s_sleep(1);
      }
      __builtin_amdgcn_fence(__ATOMIC_ACQUIRE, "agent");
    }

    const u16* hc = hbuf + ((size_t)(t & 1) * 2 + dir) * BATCH * HSZ;

    // load all A-fragments for the step (plain wide loads, full MLP)
    bf16x8 a0[16], a1[16];
#pragma unroll
    for (int kg = 0; kg < 16; kg++) {
      a0[kg] = *(const bf16x8*)&hc[(size_t)l15 * HSZ + kg * 32 + kq];
      a1[kg] = *(const bf16x8*)&hc[(size_t)(16 + l15) * HSZ + kg * 32 + kq];
    }

    f32x4 aR0 = {}, aR1 = {}, aZ0 = {}, aZ1 = {}, aN0 = {}, aN1 = {};
#pragma unroll
    for (int kg = 0; kg < 16; kg++) {
      bf16x8 wR = *(const bf16x8*)&sW[0][l15][kg * 32 + kq];
      bf16x8 wZ = *(const bf16x8*)&sW[1][l15][kg * 32 + kq];
      bf16x8 wN = *(const bf16x8*)&sW[2][l15][kg * 32 + kq];
      aR0 = __builtin_amdgcn_mfma_f32_16x16x32_bf16(a0[kg], wR, aR0, 0, 0, 0);
      aR1 = __builtin_amdgcn_mfma_f32_16x16x32_bf16(a1[kg], wR, aR1, 0, 0, 0);
      aZ0 = __builtin_amdgcn_mfma_f32_16x16x32_bf16(a0[kg], wZ, aZ0, 0, 0, 0);
      aZ1 = __builtin_amdgcn_mfma_f32_16x16x32_bf16(a1[kg], wZ, aZ1, 0, 0, 0);
      aN0 = __builtin_amdgcn_mfma_f32_16x16x32_bf16(a0[kg], wN, aN0, 0, 0, 0);
      aN1 = __builtin_amdgcn_mfma_f32_16x16x32_bf16(a1[kg], wN, aN1, 0, 0, 0);
    }

    u16* hn = hbuf + ((size_t)((t + 1) & 1) * 2 + dir) * BATCH * HSZ;
#pragma unroll
    for (int mt = 0; mt < 2; mt++)
#pragma unroll
      for (int r = 0; r < 4; r++) {
        int i = mt * 4 + r;
        int b = mt * 16 + q * 4 + r;
        float aR = mt ? aR1[r] : aR0[r];
        float aZ = mt ? aZ1[r] : aZ0[r];
        float aN = mt ? aN1[r] : aN0[r];
        float xr = gv[0][i] + aR + bhr;
        float xz = gv[1][i] + aZ + bhz;
        xr = fminf(fmaxf(xr, -40.f), 40.f);
        xz = fminf(fmaxf(xz, -40.f), 40.f);
        float rr = 1.f / (1.f + __expf(-xr));
        float zz = 1.f / (1.f + __expf(-xz));
        float xn = gv[2][i] + rr * (aN + bhn);
        xn = fminf(fmaxf(xn, -15.f), 15.f);
        float e2 = __expf(2.f * xn);
        float nn = (e2 - 1.f) / (e2 + 1.f);
        float hv = (1.f - zz) * nn + zz * hm[i];
        hm[i] = hv;

        hn[(size_t)b * HSZ + j] = f2bf(hv);
        size_t oidx = ((size_t)t_eff * BATCH + b) * 1024 + dir * HSZ + j;
        if (outF) outF[oidx] = hv;
        if (outB) outB[oidx] = f2bf(hv);
      }

    __builtin_amdgcn_fence(__ATOMIC_RELEASE, "agent");
    if (lane == 0)
      __hip_atomic_store(&flags[dir * 64 + jc], base + t + 2, __ATOMIC_RELAXED, __HIP_MEMORY_SCOPE_AGENT);
  }
}

// ---------- launch ----------
extern "C" void kernel_launch(void* const* d_in, const int* in_sizes, int n_in,
                              void* d_out, int out_size, void* d_ws, size_t ws_size,
                              hipStream_t stream)
{
  const float* x  = (const float*)d_in[0];
  const float* h0 = (const float*)d_in[1];
  const float* w_ih[3] = {(const float*)d_in[2], (const float*)d_in[6], (const float*)d_in[10]};
  const float* w_hh[3] = {(const float*)d_in[3], (const float*)d_in[7], (const float*)d_in[11]};
  const float* b_ih[3] = {(const float*)d_in[4], (const float*)d_in[8], (const float*)d_in[12]};
  const float* b_hh[3] = {(const float*)d_in[5], (const float*)d_in[9], (const float*)d_in[13]};

  char* ws = (char*)d_ws;
  size_t off = 0;
  auto alloc = [&](size_t bytes) {
    void* p = ws + off;
    off = (off + bytes + 255) & ~(size_t)255;
    return p;
  };
  int* flags = (int*)alloc(4096);
  u16* hbuf = (u16*)alloc((size_t)2 * 2 * BATCH * HSZ * 2);  // bf16 ping-pong
  u16* xbf  = (u16*)alloc((size_t)16384 * 256 * 2);
  u16* lobf = (u16*)alloc((size_t)16384 * 1024 * 2);
  u16* wihT[3];
  wihT[0] = (u16*)alloc((size_t)2 * G3 * 256 * 2);
  wihT[1] = (u16*)alloc((size_t)2 * G3 * 1024 * 2);
  wihT[2] = (u16*)alloc((size_t)2 * G3 * 1024 * 2);
  u16* whhT[3];
  for (int l = 0; l < 3; l++) whhT[l] = (u16*)alloc((size_t)2 * G3 * 512 * 2);
  _Float16* gi = (_Float16*)alloc((size_t)2 * T_LEN * BATCH * G3 * 2);

  hipMemsetAsync(flags, 0, 4096, stream);

  convert_x<<<4096, 256, 0, stream>>>(x, xbf, 16384 * 256 / 4);
  transpose_bf16<<<dim3(48, 8, 2),  256, 0, stream>>>(w_ih[0], wihT[0], 256,  G3);
  transpose_bf16<<<dim3(48, 32, 2), 256, 0, stream>>>(w_ih[1], wihT[1], 1024, G3);
  transpose_bf16<<<dim3(48, 32, 2), 256, 0, stream>>>(w_ih[2], wihT[2], 1024, G3);
  for (int l = 0; l < 3; l++)
    transpose_bf16<<<dim3(48, 16, 2), 256, 0, stream>>>(w_hh[l], whhT[l], 512, G3);

  const int M = T_LEN * BATCH;
  for (int l = 0; l < 3; l++) {
    int K = (l == 0) ? 256 : 1024;
    const u16* Ain = (l == 0) ? xbf : lobf;
    gemm_gi<<<dim3(M / 128, G3 / 128, 2), 256, 0, stream>>>(Ain, wihT[l], b_ih[l], gi, M, K);
    float* oF = (l == 2) ? (float*)d_out : nullptr;
    u16* oB = (l < 2) ? lobf : nullptr;
    gru_rec<<<64, 64, 0, stream>>>(gi, whhT[l], b_hh[l],
                                   h0 + (size_t)l * 2 * BATCH * HSZ,
                                   oF, oB, hbuf, flags, l * 513);
  }
}

// Round 5
// 7486.639 us; speedup vs baseline: 3.7124x; 1.4122x over previous
//
#include <hip/hip_runtime.h>

#define T_LEN 512
#define BATCH 32
#define HSZ 512
#define G3 1536

typedef unsigned int u32;
typedef unsigned long long u64;
typedef unsigned short u16;
typedef __attribute__((ext_vector_type(8))) short bf16x8;
typedef __attribute__((ext_vector_type(4))) float f32x4;

// ---------- helpers ----------
static __device__ __forceinline__ u16 f2bf(float x) {
  u32 u = __float_as_uint(x);
  u32 r = (u + 0x7FFFu + ((u >> 16) & 1u)) >> 16;
  return (u16)r;
}
static __device__ __forceinline__ u32 pack_bf16(float a, float b) {
  return (u32)f2bf(a) | ((u32)f2bf(b) << 16);
}
static __device__ __forceinline__ float nz(float x) { return (x == x) ? x : 0.f; }

// ---------- conversion kernels ----------
__global__ __launch_bounds__(256) void transpose_bf16(
    const float* __restrict__ src, u16* __restrict__ dst, int K, int N)
{
  int dirz = blockIdx.z;
  src += (size_t)dirz * K * N;
  dst += (size_t)dirz * N * K;
  __shared__ float tile[32][33];
  int n0 = blockIdx.x * 32, k0 = blockIdx.y * 32;
  int tx = threadIdx.x & 31, ty = threadIdx.x >> 5;
#pragma unroll
  for (int i = ty; i < 32; i += 8)
    tile[i][tx] = src[(size_t)(k0 + i) * N + n0 + tx];
  __syncthreads();
#pragma unroll
  for (int i = ty; i < 32; i += 8)
    dst[(size_t)(n0 + i) * K + k0 + tx] = f2bf(tile[tx][i]);
}

__global__ __launch_bounds__(256) void convert_x(
    const float* __restrict__ src, u16* __restrict__ dst, int n4)
{
  int i = blockIdx.x * 256 + threadIdx.x;
  if (i >= n4) return;
  float4 v = ((const float4*)src)[i];
  union { u16 h[4]; uint2 u; } o;
  o.h[0] = f2bf(v.x); o.h[1] = f2bf(v.y); o.h[2] = f2bf(v.z); o.h[3] = f2bf(v.w);
  ((uint2*)dst)[i] = o.u;
}

// ---------- input-gate GEMM (verified R3) ----------
__global__ __launch_bounds__(256) void gemm_gi(
    const u16* __restrict__ A,   // [M][K] bf16
    const u16* __restrict__ Bw,  // [2][N][K] bf16
    const float* __restrict__ bias,
    _Float16* __restrict__ C,    // [2][M][N]
    int M, int K)
{
  const int N = G3;
  int dir = blockIdx.z;
  const u16* Bd = Bw + (size_t)dir * N * K;
  _Float16* Cd = C + (size_t)dir * M * N;
  const float* biasd = bias + dir * N;

  int tm = blockIdx.x * 128;
  int tn = blockIdx.y * 128;

  __shared__ u16 sA[128][40];
  __shared__ u16 sB[128][40];

  int tid = threadIdx.x;
  int lane = tid & 63, wave = tid >> 6;
  int wm = (wave & 1) << 6, wn = (wave >> 1) << 6;

  f32x4 acc[4][4] = {};

  int srow = tid >> 1, shalf = (tid & 1) << 4;
  const u16* pa = A + (size_t)(tm + srow) * K + shalf;
  const u16* pb = Bd + (size_t)(tn + srow) * K + shalf;

  for (int k0 = 0; k0 < K; k0 += 32) {
    uint4 va0 = *(const uint4*)(pa + k0);
    uint4 va1 = *(const uint4*)(pa + k0 + 8);
    uint4 vb0 = *(const uint4*)(pb + k0);
    uint4 vb1 = *(const uint4*)(pb + k0 + 8);
    *(uint4*)&sA[srow][shalf]     = va0;
    *(uint4*)&sA[srow][shalf + 8] = va1;
    *(uint4*)&sB[srow][shalf]     = vb0;
    *(uint4*)&sB[srow][shalf + 8] = vb1;
    __syncthreads();
    int kg = (lane >> 4) << 3;
    int r16 = lane & 15;
    bf16x8 af[4], bfr[4];
#pragma unroll
    for (int f = 0; f < 4; f++) {
      af[f]  = *(const bf16x8*)&sA[wm + f * 16 + r16][kg];
      bfr[f] = *(const bf16x8*)&sB[wn + f * 16 + r16][kg];
    }
#pragma unroll
    for (int fm = 0; fm < 4; fm++)
#pragma unroll
      for (int fn = 0; fn < 4; fn++)
        acc[fm][fn] = __builtin_amdgcn_mfma_f32_16x16x32_bf16(af[fm], bfr[fn], acc[fm][fn], 0, 0, 0);
    __syncthreads();
  }

  int col4 = lane & 15, rbase = (lane >> 4) << 2;
#pragma unroll
  for (int fn = 0; fn < 4; fn++) {
    int col = tn + wn + fn * 16 + col4;
    float bv = biasd[col];
#pragma unroll
    for (int fm = 0; fm < 4; fm++) {
      int row0 = tm + wm + fm * 16 + rbase;
#pragma unroll
      for (int r = 0; r < 4; r++)
        Cd[(size_t)(row0 + r) * N + col] = (_Float16)nz(acc[fm][fn][r] + bv);
    }
  }
}

// ---------- persistent recurrent kernel ----------
// 64 blocks x 64 threads. block=(dir,jc): 16 j-cols, 32 batches, 3 gates.
// Weights LDS-resident. h transport: write-through relaxed agent atomics
// (u32 packed bf16 pairs out, u64 loads in) -> no wbl2 / no buffer_inv in loop.
// Out stores are nontemporal and AFTER flag publication (off critical path).
__global__ __launch_bounds__(64, 1) void gru_rec(
    const _Float16* __restrict__ gi,   // [2][T][B][G3] fp16
    const u16* __restrict__ whhT,      // [2][G3][HSZ] bf16
    const float* __restrict__ bhh,     // [2][G3]
    const float* __restrict__ h0,      // [2][B][HSZ]
    float* __restrict__ outF,          // [T][B][1024] or null
    u16* __restrict__ outB,            // [T][B][1024] bf16 or null
    u32* __restrict__ hbuf,            // [2 buf][2 dir][B][HSZ/2] packed bf16
    int* __restrict__ flags,           // [2][32] x 64B-padded lines
    int base)                          // layer * 513
{
  int dir = blockIdx.x >> 5;
  int jc  = blockIdx.x & 31;
  int lane = threadIdx.x;          // one wave
  int l15 = lane & 15;
  int q   = lane >> 4;             // 0..3
  int j   = jc * 16 + l15;         // output column
  int kq  = q * 8;                 // k offset within 32-k step

  __shared__ u16 sW[3][16][520];

  for (int idx = lane; idx < 48 * 64; idx += 64) {
    int row = idx >> 6, c = idx & 63;
    int g = row >> 4, jl = row & 15;
    const u16* src = whhT + ((size_t)dir * G3 + g * 512 + jc * 16 + jl) * HSZ + c * 8;
    *(uint4*)&sW[g][jl][c * 8] = *(const uint4*)src;
  }
  __syncthreads();

  float bhr = bhh[dir * G3 + j];
  float bhz = bhh[dir * G3 + 512 + j];
  float bhn = bhh[dir * G3 + 1024 + j];

  float hm[8];
#pragma unroll
  for (int mt = 0; mt < 2; mt++)
#pragma unroll
    for (int r = 0; r < 4; r++)
      hm[mt * 4 + r] = h0[((size_t)dir * BATCH + mt * 16 + q * 4 + r) * HSZ + j];

  // publish h0 into buffer 0 (write-through atomics, packed pairs)
  {
    u32* hb = hbuf + (size_t)dir * (BATCH * HSZ / 2);
#pragma unroll
    for (int i = 0; i < 8; i++) {
      int b = (i >> 2) * 16 + q * 4 + (i & 3);
      float partner = __shfl_xor(hm[i], 1);
      if (!(l15 & 1))
        __hip_atomic_store(&hb[(size_t)b * (HSZ / 2) + (j >> 1)], pack_bf16(hm[i], partner),
                           __ATOMIC_RELAXED, __HIP_MEMORY_SCOPE_AGENT);
    }
  }
  __builtin_amdgcn_fence(__ATOMIC_RELEASE, "workgroup");
  __builtin_amdgcn_s_waitcnt(0);
  if (lane == 0)
    __hip_atomic_store(&flags[(dir * 32 + jc) * 16], base + 1,
                       __ATOMIC_RELAXED, __HIP_MEMORY_SCOPE_AGENT);

  for (int t = 0; t < T_LEN; t++) {
    int t_eff = dir ? (T_LEN - 1 - t) : t;

    // gi prefetch (overlaps the poll)
    const _Float16* gib = gi + (((size_t)dir * T_LEN + t_eff) * BATCH) * G3;
    float gv[3][8];
#pragma unroll
    for (int g = 0; g < 3; g++)
#pragma unroll
      for (int i = 0; i < 8; i++) {
        int b = (i >> 2) * 16 + q * 4 + (i & 3);
        gv[g][i] = (float)gib[(size_t)b * G3 + g * 512 + j];
      }

    // barrier: wait for all 32 producers of this dir
    {
      int target = base + t + 1;
      const int* fl = &flags[(dir * 32 + (lane & 31)) * 16];
      while (true) {
        int f = __hip_atomic_load(fl, __ATOMIC_RELAXED, __HIP_MEMORY_SCOPE_AGENT);
        if (__ballot(f >= target) == ~0ull) break;
        __builtin_amdgcn_s_sleep(1);
      }
      __builtin_amdgcn_fence(__ATOMIC_ACQUIRE, "workgroup");
    }

    // h(t): L3-direct atomic u64 loads -> A fragments
    const u32* hc = hbuf + ((size_t)(t & 1) * 2 + dir) * (BATCH * HSZ / 2);
    union { u64 q[2]; bf16x8 v; } a0[16], a1[16];
#pragma unroll
    for (int kg = 0; kg < 16; kg++) {
      const u32* p0 = hc + (size_t)l15 * (HSZ / 2) + kg * 16 + (kq >> 1);
      const u32* p1 = hc + (size_t)(16 + l15) * (HSZ / 2) + kg * 16 + (kq >> 1);
      a0[kg].q[0] = __hip_atomic_load((const u64*)p0,       __ATOMIC_RELAXED, __HIP_MEMORY_SCOPE_AGENT);
      a0[kg].q[1] = __hip_atomic_load((const u64*)(p0 + 2), __ATOMIC_RELAXED, __HIP_MEMORY_SCOPE_AGENT);
      a1[kg].q[0] = __hip_atomic_load((const u64*)p1,       __ATOMIC_RELAXED, __HIP_MEMORY_SCOPE_AGENT);
      a1[kg].q[1] = __hip_atomic_load((const u64*)(p1 + 2), __ATOMIC_RELAXED, __HIP_MEMORY_SCOPE_AGENT);
    }

    f32x4 aR0 = {}, aR1 = {}, aZ0 = {}, aZ1 = {}, aN0 = {}, aN1 = {};
#pragma unroll
    for (int kg = 0; kg < 16; kg++) {
      bf16x8 wR = *(const bf16x8*)&sW[0][l15][kg * 32 + kq];
      bf16x8 wZ = *(const bf16x8*)&sW[1][l15][kg * 32 + kq];
      bf16x8 wN = *(const bf16x8*)&sW[2][l15][kg * 32 + kq];
      aR0 = __builtin_amdgcn_mfma_f32_16x16x32_bf16(a0[kg].v, wR, aR0, 0, 0, 0);
      aR1 = __builtin_amdgcn_mfma_f32_16x16x32_bf16(a1[kg].v, wR, aR1, 0, 0, 0);
      aZ0 = __builtin_amdgcn_mfma_f32_16x16x32_bf16(a0[kg].v, wZ, aZ0, 0, 0, 0);
      aZ1 = __builtin_amdgcn_mfma_f32_16x16x32_bf16(a1[kg].v, wZ, aZ1, 0, 0, 0);
      aN0 = __builtin_amdgcn_mfma_f32_16x16x32_bf16(a0[kg].v, wN, aN0, 0, 0, 0);
      aN1 = __builtin_amdgcn_mfma_f32_16x16x32_bf16(a1[kg].v, wN, aN1, 0, 0, 0);
    }

    // gates
    float hv[8];
#pragma unroll
    for (int mt = 0; mt < 2; mt++)
#pragma unroll
      for (int r = 0; r < 4; r++) {
        int i = mt * 4 + r;
        float aR = mt ? aR1[r] : aR0[r];
        float aZ = mt ? aZ1[r] : aZ0[r];
        float aN = mt ? aN1[r] : aN0[r];
        float xr = gv[0][i] + aR + bhr;
        float xz = gv[1][i] + aZ + bhz;
        xr = fminf(fmaxf(xr, -40.f), 40.f);
        xz = fminf(fmaxf(xz, -40.f), 40.f);
        float rr = 1.f / (1.f + __expf(-xr));
        float zz = 1.f / (1.f + __expf(-xz));
        float xn = gv[2][i] + rr * (aN + bhn);
        xn = fminf(fmaxf(xn, -15.f), 15.f);
        float e2 = __expf(2.f * xn);
        float nn = (e2 - 1.f) / (e2 + 1.f);
        hv[i] = (1.f - zz) * nn + zz * hm[i];
        hm[i] = hv[i];
      }

    // publish h(t+1): write-through atomics, then waitcnt, then flag
    u32* hn = hbuf + ((size_t)((t + 1) & 1) * 2 + dir) * (BATCH * HSZ / 2);
#pragma unroll
    for (int i = 0; i < 8; i++) {
      int b = (i >> 2) * 16 + q * 4 + (i & 3);
      float partner = __shfl_xor(hv[i], 1);
      if (!(l15 & 1))
        __hip_atomic_store(&hn[(size_t)b * (HSZ / 2) + (j >> 1)], pack_bf16(hv[i], partner),
                           __ATOMIC_RELAXED, __HIP_MEMORY_SCOPE_AGENT);
    }
    __builtin_amdgcn_fence(__ATOMIC_RELEASE, "workgroup");
    __builtin_amdgcn_s_waitcnt(0);
    if (lane == 0)
      __hip_atomic_store(&flags[(dir * 32 + jc) * 16], base + t + 2,
                         __ATOMIC_RELAXED, __HIP_MEMORY_SCOPE_AGENT);

    // out stores: off critical path, nontemporal
#pragma unroll
    for (int i = 0; i < 8; i++) {
      int b = (i >> 2) * 16 + q * 4 + (i & 3);
      size_t oidx = ((size_t)t_eff * BATCH + b) * 1024 + dir * HSZ + j;
      if (outF) __builtin_nontemporal_store(hv[i], &outF[oidx]);
      if (outB) __builtin_nontemporal_store(f2bf(hv[i]), &outB[oidx]);
    }
  }
}

// ---------- launch ----------
extern "C" void kernel_launch(void* const* d_in, const int* in_sizes, int n_in,
                              void* d_out, int out_size, void* d_ws, size_t ws_size,
                              hipStream_t stream)
{
  const float* x  = (const float*)d_in[0];
  const float* h0 = (const float*)d_in[1];
  const float* w_ih[3] = {(const float*)d_in[2], (const float*)d_in[6], (const float*)d_in[10]};
  const float* w_hh[3] = {(const float*)d_in[3], (const float*)d_in[7], (const float*)d_in[11]};
  const float* b_ih[3] = {(const float*)d_in[4], (const float*)d_in[8], (const float*)d_in[12]};
  const float* b_hh[3] = {(const float*)d_in[5], (const float*)d_in[9], (const float*)d_in[13]};

  char* ws = (char*)d_ws;
  size_t off = 0;
  auto alloc = [&](size_t bytes) {
    void* p = ws + off;
    off = (off + bytes + 255) & ~(size_t)255;
    return p;
  };
  int* flags = (int*)alloc(4096);                                  // 64 x 64B lines
  u32* hbuf = (u32*)alloc((size_t)2 * 2 * BATCH * (HSZ / 2) * 4);  // packed bf16 ping-pong
  u16* xbf  = (u16*)alloc((size_t)16384 * 256 * 2);
  u16* lobf = (u16*)alloc((size_t)16384 * 1024 * 2);
  u16* wihT[3];
  wihT[0] = (u16*)alloc((size_t)2 * G3 * 256 * 2);
  wihT[1] = (u16*)alloc((size_t)2 * G3 * 1024 * 2);
  wihT[2] = (u16*)alloc((size_t)2 * G3 * 1024 * 2);
  u16* whhT[3];
  for (int l = 0; l < 3; l++) whhT[l] = (u16*)alloc((size_t)2 * G3 * 512 * 2);
  _Float16* gi = (_Float16*)alloc((size_t)2 * T_LEN * BATCH * G3 * 2);

  hipMemsetAsync(flags, 0, 4096, stream);

  convert_x<<<4096, 256, 0, stream>>>(x, xbf, 16384 * 256 / 4);
  transpose_bf16<<<dim3(48, 8, 2),  256, 0, stream>>>(w_ih[0], wihT[0], 256,  G3);
  transpose_bf16<<<dim3(48, 32, 2), 256, 0, stream>>>(w_ih[1], wihT[1], 1024, G3);
  transpose_bf16<<<dim3(48, 32, 2), 256, 0, stream>>>(w_ih[2], wihT[2], 1024, G3);
  for (int l = 0; l < 3; l++)
    transpose_bf16<<<dim3(48, 16, 2), 256, 0, stream>>>(w_hh[l], whhT[l], 512, G3);

  const int M = T_LEN * BATCH;
  for (int l = 0; l < 3; l++) {
    int K = (l == 0) ? 256 : 1024;
    const u16* Ain = (l == 0) ? xbf : lobf;
    gemm_gi<<<dim3(M / 128, G3 / 128, 2), 256, 0, stream>>>(Ain, wihT[l], b_ih[l], gi, M, K);
    float* oF = (l == 2) ? (float*)d_out : nullptr;
    u16* oB = (l < 2) ? lobf : nullptr;
    gru_rec<<<64, 64, 0, stream>>>(gi, whhT[l], b_hh[l],
                                   h0 + (size_t)l * 2 * BATCH * HSZ,
                                   oF, oB, hbuf, flags, l * 513);
  }
}